// Round 8
// baseline (4546.028 us; speedup 1.0000x reference)
//
#include <hip/hip_runtime.h>
#include <hip/hip_cooperative_groups.h>
#include <hip/hip_bf16.h>

namespace cg = cooperative_groups;

#define B_ 32
#define S_ 512
#define IN_ 19
#define DE_ 256
#define DD_ 128
#define HE_ 8
#define HD_ 4
#define LE_ 6
#define LD_ 2
#define FE_ 1024
#define FD_ 512
#define DH_ 32
#define BS_ (B_ * S_)

typedef __attribute__((ext_vector_type(8))) short short8;
typedef __attribute__((ext_vector_type(4))) float f32x4;

__device__ __forceinline__ short f2bf(float f) {
    union { float f; unsigned u; } x; x.f = f;
    unsigned r = x.u + 0x7fff + ((x.u >> 16) & 1);
    return (short)(r >> 16);
}
__device__ __forceinline__ float bf2f(short s) {
    union { unsigned u; float f; } x; x.u = ((unsigned)(unsigned short)s) << 16;
    return x.f;
}

#define GLL16(g, l) __builtin_amdgcn_global_load_lds( \
    (const __attribute__((address_space(1))) void*)(g), \
    (__attribute__((address_space(3))) void*)(l), 16, 0, 0)

#define QSCALE 0.2550653169f
#define NCONV 9
#define SMBYTES 36864   // max stage need: gemm_ln N=256 staging (2*(32+256)*32*2B)

// ===========================================================================
// Tile bodies (shared by mega-kernel and fallback kernels; bit-identical math
// to the round-1-proven kernels). All are __forceinline__ so the LDS pointer
// provenance survives the addrspace(3) cast in GLL16.
// ===========================================================================

// ---- plan (256 threads, 2 positions/thread; integer-exact scan) ----
__device__ __forceinline__ void plan_tile(
    char* smc, int b, const int* am, const int* pm,
    int* counts, int* lengths, int* order, int* visible, int* idx) {
    int* sc = (int*)smc;
    int t = threadIdx.x;
    int s0 = t, s1 = t + 256;
    int a0 = (am[b * S_ + s0] != 0), v0 = a0 && (pm[b * S_ + s0] == 0);
    int a1 = (am[b * S_ + s1] != 0), v1 = a1 && (pm[b * S_ + s1] == 0);
    visible[b * S_ + s0] = v0; visible[b * S_ + s1] = v1;
    sc[s0] = v0 | (a0 << 16); sc[s1] = v1 | (a1 << 16);
    __syncthreads();
#pragma unroll
    for (int off = 1; off < S_; off <<= 1) {
        int t0 = (s0 >= off) ? sc[s0 - off] : 0;
        int t1 = (s1 >= off) ? sc[s1 - off] : 0;
        __syncthreads();
        sc[s0] += t0; sc[s1] += t1;
        __syncthreads();
    }
    int incl0 = sc[s0] & 0xffff, incl1 = sc[s1] & 0xffff;
    int tot = sc[S_ - 1];
    int total2 = tot & 0xffff;
    if (t == 0) { counts[b] = total2; lengths[b] = tot >> 16; }
    idx[b * S_ + s0] = (incl0 > 0) ? incl0 - 1 : 0;
    idx[b * S_ + s1] = (incl1 > 0) ? incl1 - 1 : 0;
    if (v0) order[b * S_ + incl0 - 1] = s0; else order[b * S_ + total2 + (s0 - incl0)] = s0;
    if (v1) order[b * S_ + incl1 - 1] = s1; else order[b * S_ + total2 + (s1 - incl1)] = s1;
    __syncthreads();   // sc reuse guard across tile iterations
}

struct ConvTab { const float* src[NCONV]; short* dst[NCONV]; int len[NCONV]; };
__device__ __forceinline__ void conv_one(const ConvTab& tab, int i) {
    int j = i;
#pragma unroll
    for (int e = 0; e < NCONV; ++e) {
        if (j < tab.len[e]) { tab.dst[e][j] = f2bf(tab.src[e][j]); return; }
        j -= tab.len[e];
    }
}

// ---- encoder embed (256 threads = DE_) ----
__device__ __forceinline__ void enc_embed_tile(
    char* smc, int bs, const float* ev, const float* w, const float* bias,
    const int* counts, const int* order, short* out) {
    float* e = (float*)smc;
    int b = bs / S_, s = bs % S_;
    int d = threadIdx.x;
    bool padded = (s >= counts[b]);
    int src = order[bs];
    if (d < IN_) e[d] = padded ? 0.f : ev[(size_t)(b * S_ + src) * IN_ + d];
    __syncthreads();
    float acc = bias[d];
#pragma unroll
    for (int i = 0; i < IN_; ++i) acc += e[i] * w[d * IN_ + i];
    out[(size_t)bs * DE_ + d] = padded ? f2bf(0.f) : f2bf(acc);
    __syncthreads();   // e reuse guard
}

// ---- decoder embed (256 threads, 2 rows/tile) ----
__device__ __forceinline__ void dec_embed_tile(
    int tile, const short* dec_vis, const float* mask_token,
    const int* visible, const int* idx, short* out) {
    int bs = tile * 2 + (threadIdx.x >> 7);
    int d = threadIdx.x & 127;
    int b = bs / S_;
    short val = visible[bs] ? dec_vis[(size_t)(b * S_ + idx[bs]) * DD_ + d]
                            : f2bf(mask_token[d]);
    out[(size_t)bs * DD_ + d] = val;
}

// ---- LDS-staged MFMA GEMM tile (R1-proven body) ----
template <int TM, int TN, bool RELU, bool QKV>
__device__ __forceinline__ void gemm_tile(
    char* smc, int bxi, int byi,
    const short* A, const short* Wt, const float* bias,
    short* C, int N, int K,
    short* qb, short* kb, short* vtb, int H, int D,
    const int* live) {
    constexpr int HM = TM / 2, HN = TN / 2;
    constexpr int MI = HM / 16, NI = HN / 16;
    constexpr int NCHA = TM / 16, NCH = (TM + TN) / 16;
    int bm = byi * TM, bn = bxi * TN;
    if (live && (bm & (S_ - 1)) >= live[bm >> 9]) return;
    short* As = (short*)smc;             // [2][TM][32]
    short* Bs = As + 2 * TM * 32;        // [2][TN][32]
    int t = threadIdx.x;
    int wave = t >> 6, lane = t & 63;
    int wm = (wave >> 1) * HM, wn = (wave & 1) * HN;
    int c = lane & 15, quad = lane >> 4;
    f32x4 acc[MI][NI];
#pragma unroll
    for (int i = 0; i < MI; ++i)
#pragma unroll
        for (int j = 0; j < NI; ++j) acc[i][j] = (f32x4){0.f, 0.f, 0.f, 0.f};
    int srow = lane >> 2, scol = (lane & 3) * 8;
    int nk = K >> 5;
    auto stage = [&](int buf, int k0) {
#pragma unroll
        for (int ch0 = 0; ch0 < NCH; ch0 += 4) {
            int ch = ch0 + wave;
            if (ch < NCHA)
                GLL16(A + (size_t)(bm + ch * 16 + srow) * K + k0 + scol,
                      As + ((size_t)buf * TM + ch * 16) * 32);
            else if (ch < NCH)
                GLL16(Wt + (size_t)(bn + (ch - NCHA) * 16 + srow) * K + k0 + scol,
                      Bs + ((size_t)buf * TN + (ch - NCHA) * 16) * 32);
        }
    };
    stage(0, 0);
    __syncthreads();
    for (int kt = 0; kt < nk; ++kt) {
        int cur = kt & 1;
        if (kt + 1 < nk) stage(cur ^ 1, (kt + 1) << 5);
        short8 av[MI], bv[NI];
#pragma unroll
        for (int mi = 0; mi < MI; ++mi)
            av[mi] = *(const short8*)(As + ((size_t)cur * TM + wm + mi * 16 + c) * 32 + quad * 8);
#pragma unroll
        for (int ni = 0; ni < NI; ++ni)
            bv[ni] = *(const short8*)(Bs + ((size_t)cur * TN + wn + ni * 16 + c) * 32 + quad * 8);
#pragma unroll
        for (int mi = 0; mi < MI; ++mi)
#pragma unroll
            for (int ni = 0; ni < NI; ++ni)
                acc[mi][ni] = __builtin_amdgcn_mfma_f32_16x16x32_bf16(av[mi], bv[ni], acc[mi][ni], 0, 0, 0);
        __syncthreads();
    }
#pragma unroll
    for (int mi = 0; mi < MI; ++mi)
#pragma unroll
        for (int ni = 0; ni < NI; ++ni)
#pragma unroll
            for (int r = 0; r < 4; ++r) {
                int R = bm + wm + mi * 16 + quad * 4 + r;
                int Ncol = bn + wn + ni * 16 + c;
                float v = acc[mi][ni][r] + (bias ? bias[Ncol] : 0.f);
                if (RELU) v = fmaxf(v, 0.f);
                if (!QKV) {
                    C[(size_t)R * N + Ncol] = f2bf(v);
                } else {
                    int s = R & (S_ - 1), b2 = R >> 9;
                    if (Ncol < D) {
                        int h = Ncol >> 5, d = Ncol & 31;
                        qb[(((size_t)b2 * H + h) * S_ + s) * DH_ + d] = f2bf(v * QSCALE);
                    } else if (Ncol < 2 * D) {
                        int n2 = Ncol - D, h = n2 >> 5, d = n2 & 31;
                        kb[(((size_t)b2 * H + h) * S_ + s) * DH_ + d] = f2bf(v);
                    } else {
                        int n2 = Ncol - 2 * D, h = n2 >> 5, d = n2 & 31;
                        vtb[(((size_t)b2 * H + h) * DH_ + d) * S_ + s] = f2bf(v);
                    }
                }
            }
}

// ---- fused GEMM + residual + LayerNorm tile (R1-proven body) ----
template <int N, bool HEAD>
__device__ __forceinline__ void gemm_ln_tile(
    char* smc, int bmTile,
    const short* A, const short* Wt, const float* bias, const short* x,
    const float* g, const float* be, short* out,
    const float* qw, const float* qbb, const float* dw, const float* dbb,
    float* outf, int K, const int* live) {
    constexpr int TM = 32;
    constexpr int HN = N / 2, NI = HN / 16;
    constexpr int NCHA = TM / 16, NCH = NCHA + N / 16;
    constexpr int HST = N + 8;
    constexpr int BUF = (TM + N) * 32;
    int bm = bmTile * TM;
    if (live && (bm & (S_ - 1)) >= live[bm >> 9]) return;
    short* smem = (short*)smc;
    int t = threadIdx.x, wave = t >> 6, lane = t & 63;
    int wm = (wave >> 1) * 16, wn = (wave & 1) * HN;
    int c = lane & 15, quad = lane >> 4;
    int srow = lane >> 2, scol = (lane & 3) * 8;
    f32x4 acc[NI];
#pragma unroll
    for (int ni = 0; ni < NI; ++ni) acc[ni] = (f32x4){0.f, 0.f, 0.f, 0.f};
    int nk = K >> 5;
    auto stage = [&](int buf, int k0) {
        short* base = smem + buf * BUF;
#pragma unroll
        for (int ch0 = 0; ch0 < NCH; ch0 += 4) {
            int ch = ch0 + wave;
            if (ch < NCHA)
                GLL16(A + (size_t)(bm + ch * 16 + srow) * K + k0 + scol, base + ch * 16 * 32);
            else if (ch < NCH)
                GLL16(Wt + (size_t)((ch - NCHA) * 16 + srow) * K + k0 + scol,
                      base + (TM + (ch - NCHA) * 16) * 32);
        }
    };
    stage(0, 0);
    __syncthreads();
    for (int kt = 0; kt < nk; ++kt) {
        int cur = kt & 1;
        if (kt + 1 < nk) stage(cur ^ 1, (kt + 1) << 5);
        const short* base = smem + cur * BUF;
        short8 av = *(const short8*)(base + (wm + c) * 32 + quad * 8);
        short8 bv[NI];
#pragma unroll
        for (int ni = 0; ni < NI; ++ni)
            bv[ni] = *(const short8*)(base + (TM + wn + ni * 16 + c) * 32 + quad * 8);
#pragma unroll
        for (int ni = 0; ni < NI; ++ni)
            acc[ni] = __builtin_amdgcn_mfma_f32_16x16x32_bf16(av, bv[ni], acc[ni], 0, 0, 0);
        __syncthreads();
    }
    // h -> LDS (identical f2bf rounding to the unfused path)
    short* Hs = smem;
#pragma unroll
    for (int ni = 0; ni < NI; ++ni) {
        int col = wn + ni * 16 + c;
        float bcol = bias[col];
#pragma unroll
        for (int r = 0; r < 4; ++r)
            Hs[(wm + quad * 4 + r) * HST + col] = f2bf(acc[ni][r] + bcol);
    }
    __syncthreads();
    // LN: 8 threads/row
    constexpr int CPL = N / 8;
    int r = t >> 3, li = t & 7;
    int R = bm + r;
    int c0 = li * CPL;
    float v[CPL];
    float s = 0.f;
#pragma unroll
    for (int e8 = 0; e8 < CPL / 8; ++e8) {
        short8 xv = *(const short8*)&x[(size_t)R * N + c0 + e8 * 8];
#pragma unroll
        for (int j = 0; j < 8; ++j) {
            float vv = bf2f(xv[j]) + bf2f(Hs[r * HST + c0 + e8 * 8 + j]);
            v[e8 * 8 + j] = vv;
            s += vv;
        }
    }
    s += __shfl_xor(s, 1); s += __shfl_xor(s, 2); s += __shfl_xor(s, 4);
    float m = s / N;
    float s2 = 0.f;
#pragma unroll
    for (int e = 0; e < CPL; ++e) { float d = v[e] - m; s2 += d * d; }
    s2 += __shfl_xor(s2, 1); s2 += __shfl_xor(s2, 2); s2 += __shfl_xor(s2, 4);
    float rstd = rsqrtf(s2 / N + 1e-5f);
    if (!HEAD) {
        bool wr = !(live && ((R & (S_ - 1)) >= live[R >> 9]));
        if (wr) {
#pragma unroll
            for (int e8 = 0; e8 < CPL / 8; ++e8) {
                short8 ov;
#pragma unroll
                for (int j = 0; j < 8; ++j) {
                    int e = e8 * 8 + j;
                    ov[j] = f2bf((v[e] - m) * rstd * g[c0 + e] + be[c0 + e]);
                }
                *(short8*)&out[(size_t)R * N + c0 + e8 * 8] = ov;
            }
        }
    } else {
        float q = 0.f, dt = 0.f;
#pragma unroll
        for (int e = 0; e < CPL; ++e) {
            float o = (v[e] - m) * rstd * g[c0 + e] + be[c0 + e];
            q += o * qw[c0 + e];
            dt += o * dw[c0 + e];
        }
        q += __shfl_xor(q, 1); q += __shfl_xor(q, 2); q += __shfl_xor(q, 4);
        dt += __shfl_xor(dt, 1); dt += __shfl_xor(dt, 2); dt += __shfl_xor(dt, 4);
        if (li == 0) {
            outf[(size_t)R * 2 + 0] = q + qbb[0];
            outf[(size_t)R * 2 + 1] = dt + dbb[0];
        }
    }
    __syncthreads();   // smem reuse guard across tile iterations
}

// ---- flash attention tile (unchanged proven body; Pt wave-private) ----
__device__ __forceinline__ void attn_tile(
    char* smc, int qt, int h, int b,
    const short* qb, const short* kb, const short* vtb,
    const int* limit_arr, const int* qlim, short* o, int H, int D) {
    if (qlim && qt * 64 >= qlim[b]) return;
    int wave = threadIdx.x >> 6, lane = threadIdx.x & 63;
    int q0 = qt * 64 + wave * 16;
    int c = lane & 15, quad = lane >> 4;
    size_t bh = (size_t)b * H + h;
    short* Pt = (short*)smc + wave * 16 * 132;     // [16][132] per wave
    f32x4 zero = (f32x4){0.f, 0.f, 0.f, 0.f};
    short8 aq = *(const short8*)&qb[(bh * S_ + q0 + c) * DH_ + quad * 8];
    const short* kbase = kb + bh * S_ * DH_;
    const short* vbase = vtb + bh * DH_ * S_;
    int limit = limit_arr[b];
    int nchunks = (limit + 127) >> 7;
    float lrow[4] = {0.f, 0.f, 0.f, 0.f};
    f32x4 o0 = zero, o1 = zero;
    for (int kc = 0; kc < nchunks; ++kc) {
        f32x4 s[8];
#pragma unroll
        for (int nt = 0; nt < 8; ++nt) {
            short8 bk = *(const short8*)&kbase[(size_t)(kc * 128 + nt * 16 + c) * DH_ + quad * 8];
            s[nt] = __builtin_amdgcn_mfma_f32_16x16x32_bf16(aq, bk, zero, 0, 0, 0);
        }
#pragma unroll
        for (int nt = 0; nt < 8; ++nt) {
            bool ok = (kc * 128 + nt * 16 + c) < limit;
#pragma unroll
            for (int r = 0; r < 4; ++r) {
                float p = ok ? exp2f(s[nt][r]) : 0.f;
                s[nt][r] = p;
                lrow[r] += p;
            }
        }
#pragma unroll
        for (int nt = 0; nt < 8; ++nt)
#pragma unroll
            for (int r = 0; r < 4; ++r)
                Pt[(quad * 4 + r) * 132 + nt * 16 + c] = f2bf(s[nt][r]);
        // wave-private; intra-wave ds ordering via lgkmcnt
#pragma unroll
        for (int kk = 0; kk < 4; ++kk) {
            short8 ap = *(const short8*)&Pt[c * 132 + kk * 32 + quad * 8];
            short8 b0 = *(const short8*)&vbase[(size_t)c * S_ + kc * 128 + kk * 32 + quad * 8];
            short8 b1 = *(const short8*)&vbase[(size_t)(16 + c) * S_ + kc * 128 + kk * 32 + quad * 8];
            o0 = __builtin_amdgcn_mfma_f32_16x16x32_bf16(ap, b0, o0, 0, 0, 0);
            o1 = __builtin_amdgcn_mfma_f32_16x16x32_bf16(ap, b1, o1, 0, 0, 0);
        }
    }
#pragma unroll
    for (int r = 0; r < 4; ++r) {
        float l = lrow[r];
        l += __shfl_xor(l, 1);
        l += __shfl_xor(l, 2);
        l += __shfl_xor(l, 4);
        l += __shfl_xor(l, 8);
        float inv = 1.f / l;
        int row = quad * 4 + r;
        size_t base = (size_t)(b * S_ + q0 + row) * D + h * DH_;
        o[base + c] = f2bf(o0[r] * inv);
        o[base + 16 + c] = f2bf(o1[r] * inv);
    }
}

// ===========================================================================
// Mega-kernel (cooperative): whole network, grid.sync between stages.
// ===========================================================================
struct MegaP {
    ConvTab tab; int convTotal;
    const int *am, *pm;
    int *counts, *lengths, *order, *visible, *idx;
    const float *ev, *w_in, *b_in, *mask_tok;
    const short *w_eqkv, *w_eout, *w_ef1, *w_ef2, *w_e2d, *w_dqkv, *w_dout, *w_df1, *w_df2;
    const float *eqkv_b, *eout_b, *ef1_b, *ef2_b, *eg1, *eb1, *eg2, *eb2;
    const float *dqkv_b, *dout_b, *df1_b, *df2_b, *dg1, *db1, *dg2, *db2;
    const float *qh_w, *qh_b, *dth_w, *dth_b;
    short *bx, *qbuf, *kbuf, *vtbuf, *battn, *bt, *hid;
    float* out;
};

#define GSYNC() do { __threadfence(); grid.sync(); __threadfence(); } while (0)
#define FORTILE(v, n) for (int v = blockIdx.x; v < (n); v += gridDim.x)

__global__ __launch_bounds__(256) void mega_kernel(MegaP p) {
    __shared__ __align__(16) char smc[SMBYTES];
    cg::grid_group grid = cg::this_grid();
    // stage A: plan + weight conv
    FORTILE(t, B_) plan_tile(smc, t, p.am, p.pm, p.counts, p.lengths, p.order, p.visible, p.idx);
    for (int i = blockIdx.x * 256 + threadIdx.x; i < p.convTotal; i += gridDim.x * 256)
        conv_one(p.tab, i);
    GSYNC();
    // stage B: encoder embed
    FORTILE(t, BS_) enc_embed_tile(smc, t, p.ev, p.w_in, p.b_in, p.counts, p.order, p.bx);
    GSYNC();
    // encoder layers
    for (int l = 0; l < LE_; ++l) {
        const short* wq = p.w_eqkv + (size_t)l * 3 * DE_ * DE_;
        FORTILE(t, 12 * 256)
            gemm_tile<64, 64, false, true>(smc, t % 12, t / 12, p.bx, wq,
                p.eqkv_b + (size_t)l * 3 * DE_, nullptr, 3 * DE_, DE_,
                p.qbuf, p.kbuf, p.vtbuf, HE_, DE_, p.counts);
        GSYNC();
        FORTILE(t, (S_ / 64) * HE_ * B_)
            attn_tile(smc, t & 7, (t >> 3) & 7, t >> 6, p.qbuf, p.kbuf, p.vtbuf,
                      p.counts, p.counts, p.battn, HE_, DE_);
        GSYNC();
        FORTILE(t, BS_ / 32)
            gemm_ln_tile<DE_, false>(smc, t, p.battn, p.w_eout + (size_t)l * DE_ * DE_,
                p.eout_b + (size_t)l * DE_, p.bx, p.eg1 + (size_t)l * DE_, p.eb1 + (size_t)l * DE_,
                p.bx, nullptr, nullptr, nullptr, nullptr, nullptr, DE_, p.counts);
        GSYNC();
        FORTILE(t, 16 * 256)
            gemm_tile<64, 64, true, false>(smc, t & 15, t >> 4, p.bx,
                p.w_ef1 + (size_t)l * FE_ * DE_, p.ef1_b + (size_t)l * FE_, p.hid, FE_, DE_,
                nullptr, nullptr, nullptr, 0, 0, p.counts);
        GSYNC();
        FORTILE(t, BS_ / 32)
            gemm_ln_tile<DE_, false>(smc, t, p.hid, p.w_ef2 + (size_t)l * DE_ * FE_,
                p.ef2_b + (size_t)l * DE_, p.bx, p.eg2 + (size_t)l * DE_, p.eb2 + (size_t)l * DE_,
                p.bx, nullptr, nullptr, nullptr, nullptr, nullptr, FE_, p.counts);
        GSYNC();
    }
    // enc -> dec
    FORTILE(t, 4 * 512)
        gemm_tile<32, 32, false, false>(smc, t & 3, t >> 2, p.bx, p.w_e2d, nullptr,
            p.bt, DD_, DE_, nullptr, nullptr, nullptr, 0, 0, p.counts);
    GSYNC();
    FORTILE(t, BS_ / 2) dec_embed_tile(t, p.bt, p.mask_tok, p.visible, p.idx, p.bx);
    GSYNC();
    // decoder layers
    for (int l = 0; l < LD_; ++l) {
        FORTILE(t, 6 * 256)
            gemm_tile<64, 64, false, true>(smc, t % 6, t / 6, p.bx,
                p.w_dqkv + (size_t)l * 3 * DD_ * DD_, p.dqkv_b + (size_t)l * 3 * DD_,
                nullptr, 3 * DD_, DD_, p.qbuf, p.kbuf, p.vtbuf, HD_, DD_, nullptr);
        GSYNC();
        FORTILE(t, (S_ / 64) * HD_ * B_)
            attn_tile(smc, t & 7, (t >> 3) & 3, t >> 5, p.qbuf, p.kbuf, p.vtbuf,
                      p.lengths, nullptr, p.battn, HD_, DD_);
        GSYNC();
        FORTILE(t, BS_ / 32)
            gemm_ln_tile<DD_, false>(smc, t, p.battn, p.w_dout + (size_t)l * DD_ * DD_,
                p.dout_b + (size_t)l * DD_, p.bx, p.dg1 + (size_t)l * DD_, p.db1 + (size_t)l * DD_,
                p.bx, nullptr, nullptr, nullptr, nullptr, nullptr, DD_, nullptr);
        GSYNC();
        FORTILE(t, 8 * 256)
            gemm_tile<64, 64, true, false>(smc, t & 7, t >> 3, p.bx,
                p.w_df1 + (size_t)l * FD_ * DD_, p.df1_b + (size_t)l * FD_, p.hid, FD_, DD_,
                nullptr, nullptr, nullptr, 0, 0, nullptr);
        GSYNC();
        if (l < LD_ - 1) {
            FORTILE(t, BS_ / 32)
                gemm_ln_tile<DD_, false>(smc, t, p.hid, p.w_df2 + (size_t)l * DD_ * FD_,
                    p.df2_b + (size_t)l * DD_, p.bx, p.dg2 + (size_t)l * DD_, p.db2 + (size_t)l * DD_,
                    p.bx, nullptr, nullptr, nullptr, nullptr, nullptr, FD_, nullptr);
            GSYNC();
        } else {
            FORTILE(t, BS_ / 32)
                gemm_ln_tile<DD_, true>(smc, t, p.hid, p.w_df2 + (size_t)l * DD_ * FD_,
                    p.df2_b + (size_t)l * DD_, p.bx, p.dg2 + (size_t)l * DD_, p.db2 + (size_t)l * DD_,
                    nullptr, p.qh_w, p.qh_b, p.dth_w, p.dth_b, p.out, FD_, nullptr);
        }
    }
}

// ===========================================================================
// Fallback kernels (non-cooperative; R1-equivalent sequence, same tile bodies)
// ===========================================================================
__global__ __launch_bounds__(256) void k_planconv(
    ConvTab tab, int total, const int* am, const int* pm,
    int* counts, int* lengths, int* order, int* visible, int* idx) {
    __shared__ __align__(16) char sm[2048];
    if (blockIdx.x < B_) {
        plan_tile(sm, blockIdx.x, am, pm, counts, lengths, order, visible, idx);
    } else {
        int i = (blockIdx.x - B_) * 256 + threadIdx.x;
        if (i < total) conv_one(tab, i);
    }
}
__global__ __launch_bounds__(256) void k_embed_enc(
    const float* ev, const float* w, const float* bias,
    const int* counts, const int* order, short* out) {
    __shared__ __align__(16) char sm[128];
    enc_embed_tile(sm, blockIdx.x, ev, w, bias, counts, order, out);
}
__global__ __launch_bounds__(256) void k_embed_dec(
    const short* dec_vis, const float* mask_token,
    const int* visible, const int* idx, short* out) {
    dec_embed_tile(blockIdx.x, dec_vis, mask_token, visible, idx, out);
}
template <int TM, int TN, bool RELU, bool QKV, int NX>
__global__ __launch_bounds__(256) void k_gemm(
    const short* A, const short* Wt, const float* bias, short* C, int N, int K,
    short* qb, short* kb, short* vtb, int H, int D, const int* live) {
    __shared__ __align__(16) char sm[2 * (TM + TN) * 32 * 2];
    gemm_tile<TM, TN, RELU, QKV>(sm, blockIdx.x % NX, blockIdx.x / NX,
                                 A, Wt, bias, C, N, K, qb, kb, vtb, H, D, live);
}
template <int N, bool HEAD>
__global__ __launch_bounds__(256) void k_gemmln(
    const short* A, const short* Wt, const float* bias, const short* x,
    const float* g, const float* be, short* out,
    const float* qw, const float* qbb, const float* dw, const float* dbb,
    float* outf, int K, const int* live) {
    __shared__ __align__(16) char sm[2 * (32 + N) * 32 * 2];
    gemm_ln_tile<N, HEAD>(sm, blockIdx.x, A, Wt, bias, x, g, be, out,
                          qw, qbb, dw, dbb, outf, K, live);
}
template <int NX, int HH>
__global__ __launch_bounds__(256) void k_attn(
    const short* qb, const short* kb, const short* vtb,
    const int* limit_arr, const int* qlim, short* o, int H, int D) {
    __shared__ __align__(16) char sm[16896];
    int t = blockIdx.x;
    attn_tile(sm, t % NX, (t / NX) % HH, t / (NX * HH), qb, kb, vtb, limit_arr, qlim, o, H, D);
}

// ===========================================================================
extern "C" void kernel_launch(void* const* d_in, const int* in_sizes, int n_in,
                              void* d_out, int out_size, void* d_ws, size_t ws_size,
                              hipStream_t stream) {
    const float* ev      = (const float*)d_in[0];
    const int*  am       = (const int*)d_in[1];
    const int*  pm       = (const int*)d_in[2];
    const float* w_in    = (const float*)d_in[3];
    const float* b_in    = (const float*)d_in[4];
    const float* eqkv_w  = (const float*)d_in[5];
    const float* eqkv_b  = (const float*)d_in[6];
    const float* eout_w  = (const float*)d_in[7];
    const float* eout_b  = (const float*)d_in[8];
    const float* ef1_w   = (const float*)d_in[9];
    const float* ef1_b   = (const float*)d_in[10];
    const float* ef2_w   = (const float*)d_in[11];
    const float* ef2_b   = (const float*)d_in[12];
    const float* eg1     = (const float*)d_in[13];
    const float* eb1     = (const float*)d_in[14];
    const float* eg2     = (const float*)d_in[15];
    const float* eb2     = (const float*)d_in[16];
    const float* mask_tok= (const float*)d_in[17];
    const float* e2d_w   = (const float*)d_in[18];
    const float* dqkv_w  = (const float*)d_in[19];
    const float* dqkv_b  = (const float*)d_in[20];
    const float* dout_w  = (const float*)d_in[21];
    const float* dout_b  = (const float*)d_in[22];
    const float* df1_w   = (const float*)d_in[23];
    const float* df1_b   = (const float*)d_in[24];
    const float* df2_w   = (const float*)d_in[25];
    const float* df2_b   = (const float*)d_in[26];
    const float* dg1     = (const float*)d_in[27];
    const float* db1     = (const float*)d_in[28];
    const float* dg2     = (const float*)d_in[29];
    const float* db2     = (const float*)d_in[30];
    const float* qh_w    = (const float*)d_in[31];
    const float* qh_b    = (const float*)d_in[32];
    const float* dth_w   = (const float*)d_in[33];
    const float* dth_b   = (const float*)d_in[34];
    float* out = (float*)d_out;

    char* ws = (char*)d_ws;
    int* counts  = (int*)ws;
    int* lengths = counts + 32;
    int* order   = lengths + 32;
    int* visible = order + BS_;
    int* idx     = visible + BS_;

    short* wb = (short*)(ws + 256 * 1024);
    const int L_eqkv = LE_ * 3 * DE_ * DE_;
    const int L_eout = LE_ * DE_ * DE_;
    const int L_ef1  = LE_ * FE_ * DE_;
    const int L_ef2  = LE_ * DE_ * FE_;
    const int L_e2d  = DD_ * DE_;
    const int L_dqkv = LD_ * 3 * DD_ * DD_;
    const int L_dout = LD_ * DD_ * DD_;
    const int L_df1  = LD_ * FD_ * DD_;
    const int L_df2  = LD_ * DD_ * FD_;
    short* w_eqkv = wb;
    short* w_eout = w_eqkv + L_eqkv;
    short* w_ef1  = w_eout + L_eout;
    short* w_ef2  = w_ef1 + L_ef1;
    short* w_e2d  = w_ef2 + L_ef2;
    short* w_dqkv = w_e2d + L_e2d;
    short* w_dout = w_dqkv + L_dqkv;
    short* w_df1  = w_dout + L_dout;
    short* w_df2  = w_df1 + L_df1;
    const int convTotal = L_eqkv + L_eout + L_ef1 + L_ef2 + L_e2d + L_dqkv + L_dout + L_df1 + L_df2;

    short* bx    = (short*)(ws + 12 * 1024 * 1024);
    short* qbuf  = bx   + (size_t)BS_ * DE_;
    short* kbuf  = qbuf + (size_t)B_ * HE_ * S_ * DH_;
    short* vtbuf = kbuf + (size_t)B_ * HE_ * S_ * DH_;
    short* battn = vtbuf + (size_t)B_ * HE_ * S_ * DH_;
    short* bt    = battn + (size_t)BS_ * DE_;
    short* hid   = bt + (size_t)BS_ * DE_;

    MegaP p;
    p.tab.src[0] = eqkv_w; p.tab.dst[0] = w_eqkv; p.tab.len[0] = L_eqkv;
    p.tab.src[1] = eout_w; p.tab.dst[1] = w_eout; p.tab.len[1] = L_eout;
    p.tab.src[2] = ef1_w;  p.tab.dst[2] = w_ef1;  p.tab.len[2] = L_ef1;
    p.tab.src[3] = ef2_w;  p.tab.dst[3] = w_ef2;  p.tab.len[3] = L_ef2;
    p.tab.src[4] = e2d_w;  p.tab.dst[4] = w_e2d;  p.tab.len[4] = L_e2d;
    p.tab.src[5] = dqkv_w; p.tab.dst[5] = w_dqkv; p.tab.len[5] = L_dqkv;
    p.tab.src[6] = dout_w; p.tab.dst[6] = w_dout; p.tab.len[6] = L_dout;
    p.tab.src[7] = df1_w;  p.tab.dst[7] = w_df1;  p.tab.len[7] = L_df1;
    p.tab.src[8] = df2_w;  p.tab.dst[8] = w_df2;  p.tab.len[8] = L_df2;
    p.convTotal = convTotal;
    p.am = am; p.pm = pm;
    p.counts = counts; p.lengths = lengths; p.order = order; p.visible = visible; p.idx = idx;
    p.ev = ev; p.w_in = w_in; p.b_in = b_in; p.mask_tok = mask_tok;
    p.w_eqkv = w_eqkv; p.w_eout = w_eout; p.w_ef1 = w_ef1; p.w_ef2 = w_ef2; p.w_e2d = w_e2d;
    p.w_dqkv = w_dqkv; p.w_dout = w_dout; p.w_df1 = w_df1; p.w_df2 = w_df2;
    p.eqkv_b = eqkv_b; p.eout_b = eout_b; p.ef1_b = ef1_b; p.ef2_b = ef2_b;
    p.eg1 = eg1; p.eb1 = eb1; p.eg2 = eg2; p.eb2 = eb2;
    p.dqkv_b = dqkv_b; p.dout_b = dout_b; p.df1_b = df1_b; p.df2_b = df2_b;
    p.dg1 = dg1; p.db1 = db1; p.dg2 = dg2; p.db2 = db2;
    p.qh_w = qh_w; p.qh_b = qh_b; p.dth_w = dth_w; p.dth_b = dth_b;
    p.bx = bx; p.qbuf = qbuf; p.kbuf = kbuf; p.vtbuf = vtbuf;
    p.battn = battn; p.bt = bt; p.hid = hid; p.out = out;

    static int g_blocks = -1;
    if (g_blocks < 0) {
        int nb = 0;
        if (hipOccupancyMaxActiveBlocksPerMultiprocessor(&nb, mega_kernel, 256, 0) != hipSuccess || nb < 1)
            nb = 0;
        if (nb > 4) nb = 4;
        g_blocks = nb * 256;        // 256 CUs on MI355X
    }

    hipError_t ce = hipErrorUnknown;
    if (g_blocks >= 256) {
        void* args[] = { &p };
        ce = hipLaunchCooperativeKernel(mega_kernel, dim3(g_blocks), dim3(256), args, 0, stream);
    }
    if (ce == hipSuccess) return;

    // ---------------- fallback: R1-equivalent multi-kernel path ----------------
    k_planconv<<<B_ + (convTotal + 255) / 256, 256, 0, stream>>>(
        p.tab, convTotal, am, pm, counts, lengths, order, visible, idx);
    k_embed_enc<<<BS_, 256, 0, stream>>>(ev, w_in, b_in, counts, order, bx);
    for (int l = 0; l < LE_; ++l) {
        k_gemm<64, 64, false, true, 12><<<12 * 256, 256, 0, stream>>>(
            bx, w_eqkv + (size_t)l * 3 * DE_ * DE_, eqkv_b + (size_t)l * 3 * DE_,
            nullptr, 3 * DE_, DE_, qbuf, kbuf, vtbuf, HE_, DE_, counts);
        k_attn<8, HE_><<<(S_ / 64) * HE_ * B_, 256, 0, stream>>>(
            qbuf, kbuf, vtbuf, counts, counts, battn, HE_, DE_);
        k_gemmln<DE_, false><<<BS_ / 32, 256, 0, stream>>>(
            battn, w_eout + (size_t)l * DE_ * DE_, eout_b + (size_t)l * DE_,
            bx, eg1 + (size_t)l * DE_, eb1 + (size_t)l * DE_, bx,
            nullptr, nullptr, nullptr, nullptr, nullptr, DE_, counts);
        k_gemm<64, 64, true, false, 16><<<16 * 256, 256, 0, stream>>>(
            bx, w_ef1 + (size_t)l * FE_ * DE_, ef1_b + (size_t)l * FE_,
            hid, FE_, DE_, nullptr, nullptr, nullptr, 0, 0, counts);
        k_gemmln<DE_, false><<<BS_ / 32, 256, 0, stream>>>(
            hid, w_ef2 + (size_t)l * DE_ * FE_, ef2_b + (size_t)l * DE_,
            bx, eg2 + (size_t)l * DE_, eb2 + (size_t)l * DE_, bx,
            nullptr, nullptr, nullptr, nullptr, nullptr, FE_, counts);
    }
    k_gemm<32, 32, false, false, 4><<<4 * 512, 256, 0, stream>>>(
        bx, w_e2d, nullptr, bt, DD_, DE_, nullptr, nullptr, nullptr, 0, 0, counts);
    k_embed_dec<<<BS_ / 2, 256, 0, stream>>>(bt, mask_tok, visible, idx, bx);
    for (int l = 0; l < LD_; ++l) {
        k_gemm<64, 64, false, true, 6><<<6 * 256, 256, 0, stream>>>(
            bx, w_dqkv + (size_t)l * 3 * DD_ * DD_, dqkv_b + (size_t)l * 3 * DD_,
            nullptr, 3 * DD_, DD_, qbuf, kbuf, vtbuf, HD_, DD_, nullptr);
        k_attn<8, HD_><<<(S_ / 64) * HD_ * B_, 256, 0, stream>>>(
            qbuf, kbuf, vtbuf, lengths, nullptr, battn, HD_, DD_);
        k_gemmln<DD_, false><<<BS_ / 32, 256, 0, stream>>>(
            battn, w_dout + (size_t)l * DD_ * DD_, dout_b + (size_t)l * DD_,
            bx, dg1 + (size_t)l * DD_, db1 + (size_t)l * DD_, bx,
            nullptr, nullptr, nullptr, nullptr, nullptr, DD_, nullptr);
        k_gemm<64, 64, true, false, 8><<<8 * 256, 256, 0, stream>>>(
            bx, w_df1 + (size_t)l * FD_ * DD_, df1_b + (size_t)l * FD_,
            hid, FD_, DD_, nullptr, nullptr, nullptr, 0, 0, nullptr);
        if (l < LD_ - 1) {
            k_gemmln<DD_, false><<<BS_ / 32, 256, 0, stream>>>(
                hid, w_df2 + (size_t)l * DD_ * FD_, df2_b + (size_t)l * DD_,
                bx, dg2 + (size_t)l * DD_, db2 + (size_t)l * DD_, bx,
                nullptr, nullptr, nullptr, nullptr, nullptr, FD_, nullptr);
        } else {
            k_gemmln<DD_, true><<<BS_ / 32, 256, 0, stream>>>(
                hid, w_df2 + (size_t)l * DD_ * FD_, df2_b + (size_t)l * DD_,
                bx, dg2 + (size_t)l * DD_, db2 + (size_t)l * DD_, nullptr,
                qh_w, qh_b, dth_w, dth_b, out, FD_, nullptr);
        }
    }
}

// Round 9
// 855.104 us; speedup vs baseline: 5.3163x; 5.3163x over previous
//
#include <hip/hip_runtime.h>
#include <hip/hip_bf16.h>

#define B_ 32
#define S_ 512
#define IN_ 19
#define DE_ 256
#define DD_ 128
#define HE_ 8
#define HD_ 4
#define LE_ 6
#define LD_ 2
#define FE_ 1024
#define FD_ 512
#define DH_ 32

typedef __attribute__((ext_vector_type(8))) short short8;
typedef __attribute__((ext_vector_type(4))) short short4v;
typedef __attribute__((ext_vector_type(4))) float f32x4;

__device__ __forceinline__ short f2bf(float f) {
    union { float f; unsigned u; } x; x.f = f;
    unsigned r = x.u + 0x7fff + ((x.u >> 16) & 1);
    return (short)(r >> 16);
}
__device__ __forceinline__ float bf2f(short s) {
    union { unsigned u; float f; } x; x.u = ((unsigned)(unsigned short)s) << 16;
    return x.f;
}

#define GLL16(g, l) __builtin_amdgcn_global_load_lds( \
    (const __attribute__((address_space(1))) void*)(g), \
    (__attribute__((address_space(3))) void*)(l), 16, 0, 0)

// (1/sqrt(32)) * log2(e), folded into Q at the QKV epilogue
#define QSCALE 0.2550653169f

// ---------------------------------------------------------------------------
// merged conv (weight fp32->bf16, VECTORIZED x4) + plan: blocks <32 plan,
// >=32 conv. All 9 segment lengths are multiples of 4, so a 4-element group
// never straddles a segment boundary; per-element f2bf identical.
// ---------------------------------------------------------------------------
#define NCONV 9
struct ConvTab {
    const float* src[NCONV];
    short* dst[NCONV];
    int len[NCONV];
};
__global__ __launch_bounds__(S_) void conv_plan_kernel(
    ConvTab tab, int total4,
    const int* __restrict__ am, const int* __restrict__ pm,
    int* __restrict__ counts, int* __restrict__ lengths, int* __restrict__ order,
    int* __restrict__ visible, int* __restrict__ idx) {
    if (blockIdx.x < B_) {
        int b = blockIdx.x, s = threadIdx.x;
        __shared__ int sc[S_];
        int a = (am[b * S_ + s] != 0);
        int v = a && (pm[b * S_ + s] == 0);
        visible[b * S_ + s] = v;
        sc[s] = v | (a << 16);
        __syncthreads();
#pragma unroll
        for (int off = 1; off < S_; off <<= 1) {
            int t = (s >= off) ? sc[s - off] : 0;
            __syncthreads();
            sc[s] += t;
            __syncthreads();
        }
        int incl = sc[s] & 0xffff;
        int tot = sc[S_ - 1];
        int total2 = tot & 0xffff;
        if (s == 0) { counts[b] = total2; lengths[b] = tot >> 16; }
        idx[b * S_ + s] = (incl > 0) ? incl - 1 : 0;
        if (v) order[b * S_ + incl - 1] = s;
        else   order[b * S_ + total2 + (s - incl)] = s;
    } else {
        int i = (blockIdx.x - B_) * S_ + threadIdx.x;
        if (i >= total4) return;
        int j = i * 4;
        for (int e = 0; e < NCONV; ++e) {
            if (j < tab.len[e]) {
                float4 v = *(const float4*)(tab.src[e] + j);
                short4v o;
                o.x = f2bf(v.x); o.y = f2bf(v.y); o.z = f2bf(v.z); o.w = f2bf(v.w);
                *(short4v*)(tab.dst[e] + j) = o;
                return;
            }
            j -= tab.len[e];
        }
    }
}

// ---------------------------------------------------------------------------
// encoder embed
// ---------------------------------------------------------------------------
__global__ __launch_bounds__(DE_) void enc_embed_kernel(
    const float* __restrict__ ev, const float* __restrict__ w, const float* __restrict__ bias,
    const int* __restrict__ counts, const int* __restrict__ order, short* __restrict__ out) {
    int bs = blockIdx.x;
    int b = bs / S_, s = bs % S_;
    int d = threadIdx.x;
    __shared__ float e[IN_];
    bool padded = (s >= counts[b]);
    int src = order[bs];
    if (threadIdx.x < IN_)
        e[threadIdx.x] = padded ? 0.f : ev[(size_t)(b * S_ + src) * IN_ + threadIdx.x];
    __syncthreads();
    float acc = bias[d];
#pragma unroll
    for (int i = 0; i < IN_; ++i) acc += e[i] * w[d * IN_ + i];
    out[(size_t)bs * DE_ + d] = padded ? f2bf(0.f) : f2bf(acc);
}

// ---------------------------------------------------------------------------
// MFMA bf16 GEMM, TMxTN tile, BK=32, GLL16 staging (proven 855.6us layout)
// + 2-phase double-buffered staging. k-ascending -> bit-identical.
// live: dead-encoder-tile skip.
// ---------------------------------------------------------------------------
template <int TM, int TN, bool RELU, bool QKV>
__global__ __launch_bounds__(256) void gemm_mfma(
    const short* __restrict__ A, const short* __restrict__ Wt, const float* __restrict__ bias,
    short* __restrict__ C, int M, int N, int K,
    short* __restrict__ qb, short* __restrict__ kb, short* __restrict__ vtb, int H, int D,
    const int* __restrict__ live) {
    constexpr int HM = TM / 2, HN = TN / 2;
    constexpr int MI = HM / 16, NI = HN / 16;
    constexpr int NCHA = TM / 16, NCH = (TM + TN) / 16;   // 16-row staging chunks
    int bm = blockIdx.y * TM, bn = blockIdx.x * TN;
    if (live && (bm & (S_ - 1)) >= live[bm >> 9]) return;   // dead encoder tile
    __shared__ short As[2][TM][32];
    __shared__ short Bs[2][TN][32];
    int t = threadIdx.x;
    int wave = t >> 6, lane = t & 63;
    int wm = (wave >> 1) * HM, wn = (wave & 1) * HN;
    int c = lane & 15, quad = lane >> 4;
    f32x4 acc[MI][NI];
#pragma unroll
    for (int i = 0; i < MI; ++i)
#pragma unroll
        for (int j = 0; j < NI; ++j) acc[i][j] = (f32x4){0.f, 0.f, 0.f, 0.f};

    int srow = lane >> 2, scol = (lane & 3) * 8;
    int nk = K >> 5;

    auto stage = [&](int buf, int k0) {
#pragma unroll
        for (int ch0 = 0; ch0 < NCH; ch0 += 4) {
            int ch = ch0 + wave;
            if (ch < NCHA)
                GLL16(A + (size_t)(bm + ch * 16 + srow) * K + k0 + scol, &As[buf][ch * 16][0]);
            else if (ch < NCH)
                GLL16(Wt + (size_t)(bn + (ch - NCHA) * 16 + srow) * K + k0 + scol,
                      &Bs[buf][(ch - NCHA) * 16][0]);
        }
    };

    stage(0, 0);
    __syncthreads();
    for (int kt = 0; kt < nk; ++kt) {
        int cur = kt & 1;
        if (kt + 1 < nk) stage(cur ^ 1, (kt + 1) << 5);
        short8 av[MI], bv[NI];
#pragma unroll
        for (int mi = 0; mi < MI; ++mi) av[mi] = *(const short8*)&As[cur][wm + mi * 16 + c][quad * 8];
#pragma unroll
        for (int ni = 0; ni < NI; ++ni) bv[ni] = *(const short8*)&Bs[cur][wn + ni * 16 + c][quad * 8];
#pragma unroll
        for (int mi = 0; mi < MI; ++mi)
#pragma unroll
            for (int ni = 0; ni < NI; ++ni)
                acc[mi][ni] = __builtin_amdgcn_mfma_f32_16x16x32_bf16(av[mi], bv[ni], acc[mi][ni], 0, 0, 0);
        __syncthreads();
    }
#pragma unroll
    for (int mi = 0; mi < MI; ++mi)
#pragma unroll
        for (int ni = 0; ni < NI; ++ni)
#pragma unroll
            for (int r = 0; r < 4; ++r) {
                int R = bm + wm + mi * 16 + quad * 4 + r;
                int Ncol = bn + wn + ni * 16 + c;
                float v = acc[mi][ni][r] + (bias ? bias[Ncol] : 0.f);
                if (RELU) v = fmaxf(v, 0.f);
                if (!QKV) {
                    C[(size_t)R * N + Ncol] = f2bf(v);
                } else {
                    int s = R & (S_ - 1), b2 = R >> 9;
                    if (Ncol < D) {
                        int h = Ncol >> 5, d = Ncol & 31;
                        qb[(((size_t)b2 * H + h) * S_ + s) * DH_ + d] = f2bf(v * QSCALE);
                    } else if (Ncol < 2 * D) {
                        int n2 = Ncol - D, h = n2 >> 5, d = n2 & 31;
                        kb[(((size_t)b2 * H + h) * S_ + s) * DH_ + d] = f2bf(v);
                    } else {
                        int n2 = Ncol - 2 * D, h = n2 >> 5, d = n2 & 31;
                        vtb[(((size_t)b2 * H + h) * DH_ + d) * S_ + s] = f2bf(v);
                    }
                }
            }
}

// ---------------------------------------------------------------------------
// Fused GEMM (TM=32, TN=N full row) + residual add + LayerNorm epilogue.
// Proven 855.6us version: block owns complete rows, LN reduces in-block
// (h staged in LDS as bf16 with the SAME f2bf rounding the unfused path
// used). HEAD variant fuses the final q/dt heads.
// ---------------------------------------------------------------------------
template <int N, bool HEAD>
__global__ __launch_bounds__(256) void gemm_ln(
    const short* __restrict__ A, const short* __restrict__ Wt,
    const float* __restrict__ bias, const short* x /* residual (may alias out) */,
    const float* __restrict__ g, const float* __restrict__ be,
    short* out,
    const float* __restrict__ qw, const float* __restrict__ qbb,
    const float* __restrict__ dw, const float* __restrict__ dbb,
    float* __restrict__ outf,
    int K, const int* __restrict__ live) {
    constexpr int TM = 32;
    constexpr int HN = N / 2, NI = HN / 16;
    constexpr int NCHA = TM / 16, NCH = NCHA + N / 16;
    constexpr int HST = N + 8;                 // bf16 h-tile stride (LDS reuse)
    constexpr int BUF = (TM + N) * 32;         // shorts per staging buffer
    int bm = blockIdx.x * TM;
    if (live && (bm & (S_ - 1)) >= live[bm >> 9]) return;
    __shared__ short smem[2 * BUF];
    int t = threadIdx.x, wave = t >> 6, lane = t & 63;
    int wm = (wave >> 1) * 16, wn = (wave & 1) * HN;
    int c = lane & 15, quad = lane >> 4;
    int srow = lane >> 2, scol = (lane & 3) * 8;
    f32x4 acc[NI];
#pragma unroll
    for (int ni = 0; ni < NI; ++ni) acc[ni] = (f32x4){0.f, 0.f, 0.f, 0.f};
    int nk = K >> 5;

    auto stage = [&](int buf, int k0) {
        short* base = smem + buf * BUF;
#pragma unroll
        for (int ch0 = 0; ch0 < NCH; ch0 += 4) {
            int ch = ch0 + wave;
            if (ch < NCHA)
                GLL16(A + (size_t)(bm + ch * 16 + srow) * K + k0 + scol, base + ch * 16 * 32);
            else if (ch < NCH)
                GLL16(Wt + (size_t)((ch - NCHA) * 16 + srow) * K + k0 + scol,
                      base + (TM + (ch - NCHA) * 16) * 32);
        }
    };

    stage(0, 0);
    __syncthreads();
    for (int kt = 0; kt < nk; ++kt) {
        int cur = kt & 1;
        if (kt + 1 < nk) stage(cur ^ 1, (kt + 1) << 5);
        const short* base = smem + cur * BUF;
        short8 av = *(const short8*)(base + (wm + c) * 32 + quad * 8);
        short8 bv[NI];
#pragma unroll
        for (int ni = 0; ni < NI; ++ni)
            bv[ni] = *(const short8*)(base + (TM + wn + ni * 16 + c) * 32 + quad * 8);
#pragma unroll
        for (int ni = 0; ni < NI; ++ni)
            acc[ni] = __builtin_amdgcn_mfma_f32_16x16x32_bf16(av, bv[ni], acc[ni], 0, 0, 0);
        __syncthreads();
    }

    // ---- h -> LDS (bf16, identical rounding to the unfused bt write) ----
    short* Hs = smem;   // staging buffers are dead after the final barrier
#pragma unroll
    for (int ni = 0; ni < NI; ++ni) {
        int col = wn + ni * 16 + c;
        float bcol = bias[col];
#pragma unroll
        for (int r = 0; r < 4; ++r)
            Hs[(wm + quad * 4 + r) * HST + col] = f2bf(acc[ni][r] + bcol);
    }
    __syncthreads();

    // ---- LN phase: 8 threads per row, CPL contiguous cols each ----
    constexpr int CPL = N / 8;
    int r = t >> 3, li = t & 7;
    int R = bm + r;
    int c0 = li * CPL;
    float v[CPL];
    float s = 0.f;
#pragma unroll
    for (int e8 = 0; e8 < CPL / 8; ++e8) {
        short8 xv = *(const short8*)&x[(size_t)R * N + c0 + e8 * 8];
#pragma unroll
        for (int j = 0; j < 8; ++j) {
            float vv = bf2f(xv[j]) + bf2f(Hs[r * HST + c0 + e8 * 8 + j]);
            v[e8 * 8 + j] = vv;
            s += vv;
        }
    }
    s += __shfl_xor(s, 1); s += __shfl_xor(s, 2); s += __shfl_xor(s, 4);
    float m = s / N;
    float s2 = 0.f;
#pragma unroll
    for (int e = 0; e < CPL; ++e) { float d = v[e] - m; s2 += d * d; }
    s2 += __shfl_xor(s2, 1); s2 += __shfl_xor(s2, 2); s2 += __shfl_xor(s2, 4);
    float rstd = rsqrtf(s2 / N + 1e-5f);
    if (!HEAD) {
        if (live && ((R & (S_ - 1)) >= live[R >> 9])) return;  // dead row: skip write
#pragma unroll
        for (int e8 = 0; e8 < CPL / 8; ++e8) {
            short8 ov;
#pragma unroll
            for (int j = 0; j < 8; ++j) {
                int e = e8 * 8 + j;
                ov[j] = f2bf((v[e] - m) * rstd * g[c0 + e] + be[c0 + e]);
            }
            *(short8*)&out[(size_t)R * N + c0 + e8 * 8] = ov;
        }
    } else {
        float q = 0.f, dt = 0.f;
#pragma unroll
        for (int e = 0; e < CPL; ++e) {
            float o = (v[e] - m) * rstd * g[c0 + e] + be[c0 + e];
            q += o * qw[c0 + e];
            dt += o * dw[c0 + e];
        }
        q += __shfl_xor(q, 1); q += __shfl_xor(q, 2); q += __shfl_xor(q, 4);
        dt += __shfl_xor(dt, 1); dt += __shfl_xor(dt, 2); dt += __shfl_xor(dt, 4);
        if (li == 0) {
            outf[(size_t)R * 2 + 0] = q + qbb[0];
            outf[(size_t)R * 2 + 1] = dt + dbb[0];
        }
    }
}

// ---------------------------------------------------------------------------
// Flash MFMA attention, prefix-mask chunk skipping; optional q-tile skipping.
// ---------------------------------------------------------------------------
__global__ __launch_bounds__(256) void attn_flash(
    const short* __restrict__ qb, const short* __restrict__ kb, const short* __restrict__ vtb,
    const int* __restrict__ limit_arr, const int* __restrict__ qlim,
    short* __restrict__ o, int H, int D) {
    int b = blockIdx.z, h = blockIdx.y;
    if (qlim && (int)(blockIdx.x * 64) >= qlim[b]) return;
    int wave = threadIdx.x >> 6, lane = threadIdx.x & 63;
    int q0 = blockIdx.x * 64 + wave * 16;
    int c = lane & 15, quad = lane >> 4;
    size_t bh = (size_t)b * H + h;
    __shared__ short PtAll[4][16][132];
    short (*Pt)[132] = PtAll[wave];

    f32x4 zero = (f32x4){0.f, 0.f, 0.f, 0.f};
    short8 aq = *(const short8*)&qb[(bh * S_ + q0 + c) * DH_ + quad * 8];
    const short* kbase = kb + bh * S_ * DH_;
    const short* vbase = vtb + bh * DH_ * S_;

    int limit = limit_arr[b];
    int nchunks = (limit + 127) >> 7;

    float lrow[4] = {0.f, 0.f, 0.f, 0.f};
    f32x4 o0 = zero, o1 = zero;

    for (int kc = 0; kc < nchunks; ++kc) {
        f32x4 s[8];
#pragma unroll
        for (int nt = 0; nt < 8; ++nt) {
            short8 bk = *(const short8*)&kbase[(size_t)(kc * 128 + nt * 16 + c) * DH_ + quad * 8];
            s[nt] = __builtin_amdgcn_mfma_f32_16x16x32_bf16(aq, bk, zero, 0, 0, 0);
        }
#pragma unroll
        for (int nt = 0; nt < 8; ++nt) {
            bool ok = (kc * 128 + nt * 16 + c) < limit;
#pragma unroll
            for (int r = 0; r < 4; ++r) {
                float p = ok ? exp2f(s[nt][r]) : 0.f;
                s[nt][r] = p;
                lrow[r] += p;
            }
        }
#pragma unroll
        for (int nt = 0; nt < 8; ++nt)
#pragma unroll
            for (int r = 0; r < 4; ++r)
                Pt[quad * 4 + r][nt * 16 + c] = f2bf(s[nt][r]);
        // no barrier: Pt is wave-private, intra-wave ds ordering via lgkmcnt
#pragma unroll
        for (int kk = 0; kk < 4; ++kk) {
            short8 ap = *(const short8*)&Pt[c][kk * 32 + quad * 8];
            short8 b0 = *(const short8*)&vbase[(size_t)c * S_ + kc * 128 + kk * 32 + quad * 8];
            short8 b1 = *(const short8*)&vbase[(size_t)(16 + c) * S_ + kc * 128 + kk * 32 + quad * 8];
            o0 = __builtin_amdgcn_mfma_f32_16x16x32_bf16(ap, b0, o0, 0, 0, 0);
            o1 = __builtin_amdgcn_mfma_f32_16x16x32_bf16(ap, b1, o1, 0, 0, 0);
        }
    }
#pragma unroll
    for (int r = 0; r < 4; ++r) {
        float l = lrow[r];
        l += __shfl_xor(l, 1);
        l += __shfl_xor(l, 2);
        l += __shfl_xor(l, 4);
        l += __shfl_xor(l, 8);
        float inv = 1.f / l;
        int row = quad * 4 + r;
        size_t base = (size_t)(b * S_ + q0 + row) * D + h * DH_;
        o[base + c] = f2bf(o0[r] * inv);
        o[base + 16 + c] = f2bf(o1[r] * inv);
    }
}

// ---------------------------------------------------------------------------
// decoder embed
// ---------------------------------------------------------------------------
__global__ __launch_bounds__(DD_) void dec_embed_kernel(
    const short* __restrict__ dec_vis, const float* __restrict__ mask_token,
    const int* __restrict__ visible, const int* __restrict__ idx, short* __restrict__ out) {
    int bs = blockIdx.x, d = threadIdx.x;
    int b = bs / S_;
    short val = visible[bs] ? dec_vis[(size_t)(b * S_ + idx[bs]) * DD_ + d]
                            : f2bf(mask_token[d]);
    out[(size_t)bs * DD_ + d] = val;
}

// ---------------------------------------------------------------------------
extern "C" void kernel_launch(void* const* d_in, const int* in_sizes, int n_in,
                              void* d_out, int out_size, void* d_ws, size_t ws_size,
                              hipStream_t stream) {
    const float* ev      = (const float*)d_in[0];
    const int*  am       = (const int*)d_in[1];
    const int*  pm       = (const int*)d_in[2];
    const float* w_in    = (const float*)d_in[3];
    const float* b_in    = (const float*)d_in[4];
    const float* eqkv_w  = (const float*)d_in[5];
    const float* eqkv_b  = (const float*)d_in[6];
    const float* eout_w  = (const float*)d_in[7];
    const float* eout_b  = (const float*)d_in[8];
    const float* ef1_w   = (const float*)d_in[9];
    const float* ef1_b   = (const float*)d_in[10];
    const float* ef2_w   = (const float*)d_in[11];
    const float* ef2_b   = (const float*)d_in[12];
    const float* eg1     = (const float*)d_in[13];
    const float* eb1     = (const float*)d_in[14];
    const float* eg2     = (const float*)d_in[15];
    const float* eb2     = (const float*)d_in[16];
    const float* mask_tok= (const float*)d_in[17];
    const float* e2d_w   = (const float*)d_in[18];
    const float* dqkv_w  = (const float*)d_in[19];
    const float* dqkv_b  = (const float*)d_in[20];
    const float* dout_w  = (const float*)d_in[21];
    const float* dout_b  = (const float*)d_in[22];
    const float* df1_w   = (const float*)d_in[23];
    const float* df1_b   = (const float*)d_in[24];
    const float* df2_w   = (const float*)d_in[25];
    const float* df2_b   = (const float*)d_in[26];
    const float* dg1     = (const float*)d_in[27];
    const float* db1     = (const float*)d_in[28];
    const float* dg2     = (const float*)d_in[29];
    const float* db2     = (const float*)d_in[30];
    const float* qh_w    = (const float*)d_in[31];
    const float* qh_b    = (const float*)d_in[32];
    const float* dth_w   = (const float*)d_in[33];
    const float* dth_b   = (const float*)d_in[34];
    float* out = (float*)d_out;

    const int BS = B_ * S_;
    char* ws = (char*)d_ws;
    int* counts  = (int*)ws;
    int* lengths = counts + 32;
    int* order   = lengths + 32;
    int* visible = order + BS;
    int* idx     = visible + BS;

    short* wb = (short*)(ws + 256 * 1024);
    const int L_eqkv = LE_ * 3 * DE_ * DE_;
    const int L_eout = LE_ * DE_ * DE_;
    const int L_ef1  = LE_ * FE_ * DE_;
    const int L_ef2  = LE_ * DE_ * FE_;
    const int L_e2d  = DD_ * DE_;
    const int L_dqkv = LD_ * 3 * DD_ * DD_;
    const int L_dout = LD_ * DD_ * DD_;
    const int L_df1  = LD_ * FD_ * DD_;
    const int L_df2  = LD_ * DD_ * FD_;
    short* w_eqkv = wb;
    short* w_eout = w_eqkv + L_eqkv;
    short* w_ef1  = w_eout + L_eout;
    short* w_ef2  = w_ef1 + L_ef1;
    short* w_e2d  = w_ef2 + L_ef2;
    short* w_dqkv = w_e2d + L_e2d;
    short* w_dout = w_dqkv + L_dqkv;
    short* w_df1  = w_dout + L_dout;
    short* w_df2  = w_df1 + L_df1;
    const int convTotal = L_eqkv + L_eout + L_ef1 + L_ef2 + L_e2d + L_dqkv + L_dout + L_df1 + L_df2;
    const int convT4 = convTotal / 4;

    short* bx    = (short*)(ws + 12 * 1024 * 1024);
    short* qbuf  = bx   + (size_t)BS * DE_;
    short* kbuf  = qbuf + (size_t)B_ * HE_ * S_ * DH_;
    short* vtbuf = kbuf + (size_t)B_ * HE_ * S_ * DH_;
    short* battn = vtbuf + (size_t)B_ * HE_ * S_ * DH_;
    short* bt    = battn + (size_t)BS * DE_;
    short* hid   = bt + (size_t)BS * DE_;

    ConvTab tab;
    tab.src[0] = eqkv_w; tab.dst[0] = w_eqkv; tab.len[0] = L_eqkv;
    tab.src[1] = eout_w; tab.dst[1] = w_eout; tab.len[1] = L_eout;
    tab.src[2] = ef1_w;  tab.dst[2] = w_ef1;  tab.len[2] = L_ef1;
    tab.src[3] = ef2_w;  tab.dst[3] = w_ef2;  tab.len[3] = L_ef2;
    tab.src[4] = e2d_w;  tab.dst[4] = w_e2d;  tab.len[4] = L_e2d;
    tab.src[5] = dqkv_w; tab.dst[5] = w_dqkv; tab.len[5] = L_dqkv;
    tab.src[6] = dout_w; tab.dst[6] = w_dout; tab.len[6] = L_dout;
    tab.src[7] = df1_w;  tab.dst[7] = w_df1;  tab.len[7] = L_df1;
    tab.src[8] = df2_w;  tab.dst[8] = w_df2;  tab.len[8] = L_df2;
    conv_plan_kernel<<<B_ + (convT4 + S_ - 1) / S_, S_, 0, stream>>>(
        tab, convT4, am, pm, counts, lengths, order, visible, idx);
    enc_embed_kernel<<<BS, DE_, 0, stream>>>(ev, w_in, b_in, counts, order, bx);

    // -------------------- encoder (dead tiles skipped via counts) ----------
    for (int l = 0; l < LE_; ++l) {
        gemm_mfma<64, 64, false, true><<<dim3(3 * DE_ / 64, BS / 64), 256, 0, stream>>>(
            bx, w_eqkv + (size_t)l * 3 * DE_ * DE_, eqkv_b + (size_t)l * 3 * DE_,
            nullptr, BS, 3 * DE_, DE_, qbuf, kbuf, vtbuf, HE_, DE_, counts);
        attn_flash<<<dim3(S_ / 64, HE_, B_), 256, 0, stream>>>(
            qbuf, kbuf, vtbuf, counts, counts, battn, HE_, DE_);
        gemm_ln<DE_, false><<<BS / 32, 256, 0, stream>>>(
            battn, w_eout + (size_t)l * DE_ * DE_, eout_b + (size_t)l * DE_,
            bx, eg1 + (size_t)l * DE_, eb1 + (size_t)l * DE_, bx,
            nullptr, nullptr, nullptr, nullptr, nullptr, DE_, counts);
        gemm_mfma<64, 64, true, false><<<dim3(FE_ / 64, BS / 64), 256, 0, stream>>>(
            bx, w_ef1 + (size_t)l * FE_ * DE_, ef1_b + (size_t)l * FE_,
            hid, BS, FE_, DE_, nullptr, nullptr, nullptr, 0, 0, counts);
        gemm_ln<DE_, false><<<BS / 32, 256, 0, stream>>>(
            hid, w_ef2 + (size_t)l * DE_ * FE_, ef2_b + (size_t)l * DE_,
            bx, eg2 + (size_t)l * DE_, eb2 + (size_t)l * DE_, bx,
            nullptr, nullptr, nullptr, nullptr, nullptr, FE_, counts);
    }

    // -------------------- enc -> dec --------------------
    gemm_mfma<32, 32, false, false><<<dim3(DD_ / 32, BS / 32), 256, 0, stream>>>(
        bx, w_e2d, nullptr, bt, BS, DD_, DE_, nullptr, nullptr, nullptr, 0, 0, counts);
    dec_embed_kernel<<<BS, DD_, 0, stream>>>(bt, mask_tok, visible, idx, bx);

    // -------------------- decoder (all rows live) --------------------
    for (int l = 0; l < LD_; ++l) {
        gemm_mfma<64, 64, false, true><<<dim3(3 * DD_ / 64, BS / 64), 256, 0, stream>>>(
            bx, w_dqkv + (size_t)l * 3 * DD_ * DD_, dqkv_b + (size_t)l * 3 * DD_, nullptr,
            BS, 3 * DD_, DD_, qbuf, kbuf, vtbuf, HD_, DD_, nullptr);
        attn_flash<<<dim3(S_ / 64, HD_, B_), 256, 0, stream>>>(
            qbuf, kbuf, vtbuf, lengths, nullptr, battn, HD_, DD_);
        gemm_ln<DD_, false><<<BS / 32, 256, 0, stream>>>(
            battn, w_dout + (size_t)l * DD_ * DD_, dout_b + (size_t)l * DD_,
            bx, dg1 + (size_t)l * DD_, db1 + (size_t)l * DD_, bx,
            nullptr, nullptr, nullptr, nullptr, nullptr, DD_, nullptr);
        gemm_mfma<64, 64, true, false><<<dim3(FD_ / 64, BS / 64), 256, 0, stream>>>(
            bx, w_df1 + (size_t)l * FD_ * DD_, df1_b + (size_t)l * FD_,
            hid, BS, FD_, DD_, nullptr, nullptr, nullptr, 0, 0, nullptr);
        if (l < LD_ - 1) {
            gemm_ln<DD_, false><<<BS / 32, 256, 0, stream>>>(
                hid, w_df2 + (size_t)l * DD_ * FD_, df2_b + (size_t)l * DD_,
                bx, dg2 + (size_t)l * DD_, db2 + (size_t)l * DD_, bx,
                nullptr, nullptr, nullptr, nullptr, nullptr, FD_, nullptr);
        } else {
            gemm_ln<DD_, true><<<BS / 32, 256, 0, stream>>>(
                hid, w_df2 + (size_t)l * DD_ * FD_, df2_b + (size_t)l * DD_,
                bx, dg2 + (size_t)l * DD_, db2 + (size_t)l * DD_, nullptr,
                qh_w, qh_b, dth_w, dth_b, out, FD_, nullptr);
        }
    }
}